// Round 2
// baseline (906.537 us; speedup 1.0000x reference)
//
#include <hip/hip_runtime.h>
#include <hip/hip_bf16.h>

typedef __bf16 bf16x8 __attribute__((ext_vector_type(8)));
typedef float  f32x4  __attribute__((ext_vector_type(4)));

#define MFMA16(a,b,c) __builtin_amdgcn_mfma_f32_16x16x32_bf16((a),(b),(c),0,0,0)

__device__ __forceinline__ bf16x8 cvt8(f32x4 a, f32x4 b){
  bf16x8 r;
  r[0]=(__bf16)a[0]; r[1]=(__bf16)a[1]; r[2]=(__bf16)a[2]; r[3]=(__bf16)a[3];
  r[4]=(__bf16)b[0]; r[5]=(__bf16)b[1]; r[6]=(__bf16)b[2]; r[7]=(__bf16)b[3];
  return r;
}
__device__ __forceinline__ bf16x8 ld8(const float* p){
  return cvt8(*(const f32x4*)p, *(const f32x4*)(p+4));
}
__device__ __forceinline__ float sigm(float x){
  return __builtin_amdgcn_rcpf(1.f + __expf(-x));
}
__device__ __forceinline__ float tanhx(float x){
  return 1.f - 2.f*__builtin_amdgcn_rcpf(1.f + __expf(2.f*x));
}
__device__ __forceinline__ f32x4 sp(float v){ return (f32x4){v,v,v,v}; }

// lane^8 exchange within each 16-lane row: DPP row_ror:8 (VALU pipe, no LDS)
__device__ __forceinline__ float dppx8(float v){
  return __int_as_float(__builtin_amdgcn_update_dpp(
      0, __float_as_int(v), 0x128, 0xF, 0xF, true));
}
// lane^4 exchange: ds_swizzle xor-4 (decoder only)
__device__ __forceinline__ float swz4(float v){
  return __int_as_float(__builtin_amdgcn_ds_swizzle(__float_as_int(v), 0x101F));
}

// R2: anti-phase 2-barrier schedule (overlap GEMM-LDS-burst of one group with
// EW-VALU-tail of the other) + in-register DPP EW (no gate LDS round-trip) +
// canonical conflict-free LDS: row strides XA=128 / H1s=64 bf16 (== 0 mod 32
// dwords) with XOR group swizzle phys_group = G ^ row, so bank group =
// 4*(G^row) mod 32 is distinct across the 8 rows for every access pattern
// (b128 reads, EW bf16 scatter stores, emb stores) at any wave granularity.
// Phase A: grp0 read+MFMA L0(I+1) (+emb); grp1 EW+store h1(I-1).
// Phase B: grp0 EW+store h0(I+1);        grp1 read+MFMA L1(I).
extern "C" __global__ void __launch_bounds__(1024, 4)
seq2seq_kernel(const float* __restrict__ X,
               const float* __restrict__ Wemb, const float* __restrict__ bemb,
               const float* __restrict__ eWih, const float* __restrict__ eWhh,
               const float* __restrict__ ebih, const float* __restrict__ ebhh,
               const float* __restrict__ dWih, const float* __restrict__ dWhh,
               const float* __restrict__ dbih, const float* __restrict__ dbhh,
               const float* __restrict__ Wreg, const float* __restrict__ breg,
               float* __restrict__ out)
{
  // XA[parity][row][128]: phys groups 0-7 = x (logical G^row), 8-15 = h0.
  __shared__ __align__(16) __bf16 XA[2][8][128];
  __shared__ __align__(16) __bf16 H1s[2][8][64];

  const int tid  = (int)threadIdx.x;
  const int w    = tid >> 6;         // 0..15
  const int grp  = w >> 3;           // 0: layer0 group, 1: layer1 group
  const bool g0  = (grp == 0);
  const int wt   = w & 7;            // wave-in-group; units u0 = 8*wt
  const int lane = tid & 63;
  const int col  = lane & 15;
  const int quad = lane >> 4;
  const int row8 = col & 7;          // A real row (M=16 mirrors 8 rows)
  const int b0   = (int)blockIdx.x * 8;
  const int brow = b0 + row8;

  // fused-EW lane roles (encoder): cell = (row ewr, unit ewu)
  const bool hib = (col & 8) != 0;       // sr bit0
  const bool qhb = (quad & 2) != 0;      // sr bit1
  const int  ewr = 4*(quad & 1) + (hib ? 1 : 0) + (qhb ? 2 : 0);
  const int  ewu = 8*wt + (col & 7);

  // swizzled lane-constant offsets (bf16 elements)
  const int rx  = row8 * 128;                 // XA row base
  const int rh  = row8 * 64;                  // H1s row base
  const int gA0 = ((quad    ) ^ row8) * 8;    // logical K-group quad
  const int gA1 = ((quad + 4) ^ row8) * 8;    // logical K-group quad+4
  const int sw0 = ewr*128 + 64 + ((wt ^ ewr) << 3) + (ewu & 7);  // h0 store
  const int sw1 = ewr*64       + ((wt ^ ewr) << 3) + (ewu & 7);  // h1 store

  for (int i = tid; i < 2*8*128; i += 1024) (&XA[0][0][0])[i]  = (__bf16)0.f;
  for (int i = tid; i < 2*8*64;  i += 1024) (&H1s[0][0][0])[i] = (__bf16)0.f;

  // ---- persistent fragments: 2 tiles x 4 ksteps = 32 regs ----
  // gate-permuted col: n = 64*gate + unit, gate = 2*ti + (col>>3)
  bf16x8 wf[8];
  float  gb[2];
#pragma unroll
  for (int ti=0; ti<2; ++ti){
    const int n = 64*(2*ti + (col>>3)) + 8*wt + (col&7);
    gb[ti] = ebih[grp*256+n] + ebhh[grp*256+n];
#pragma unroll
    for (int ks=0; ks<4; ++ks){
      const float* srcw = (ks < 2) ? eWih : eWhh;
      wf[ti*4+ks] = ld8(srcw + ((size_t)(grp*256+n))*64 + (ks&1)*32 + quad*8);
    }
  }

  // emb fragments: only waves 0-3 use them
  const int ue  = (w&3)*16 + col;
  const int gue = ue >> 3, oue = ue & 7;
  bf16x8 wembf;
  float eb = 0.f;
  const float* xb = X + (size_t)brow*512*32 + quad*8;
  f32x4 pa0, pb0, pa1, pb1;
  if (w < 4){
    wembf = ld8(Wemb + ue*32 + quad*8);
    eb = bemb[ue];
    pa1 = *(const f32x4*)(xb+32); pb1 = *(const f32x4*)(xb+36);   // x(1)
    pa0 = *(const f32x4*)(xb+64); pb0 = *(const f32x4*)(xb+68);   // x(2)
  }

  float cC = 0.f;       // grp0: c0 of cell (ewr,ewu); grp1: c1
  f32x4 A0h, A1h;       // gates held across a barrier (both groups)

  // in-register EW: gather (i,f,g,o) for this lane's cell via DPP xor-8.
  auto EWF = [&](float& c) -> float {
    float lo0 = qhb ? A0h[2] : A0h[0];
    float hi0 = qhb ? A0h[3] : A0h[1];
    float lo1 = qhb ? A1h[2] : A1h[0];
    float hi1 = qhb ? A1h[3] : A1h[1];
    float a0s = hib ? hi0 : lo0, a0x = hib ? lo0 : hi0;
    float a1s = hib ? hi1 : lo1, a1x = hib ? lo1 : hi1;
    float r0 = dppx8(a0x), r1 = dppx8(a1x);
    float gi = hib ? r0  : a0s;
    float gf = hib ? a0s : r0;
    float gg = hib ? r1  : a1s;
    float go = hib ? a1s : r1;
    float i0 = sigm(gi), f0 = sigm(gf), gt = tanhx(gg), o0 = sigm(go);
    c = f0*c + i0*gt;
    return o0*tanhx(c);
  };

  // grp0 phase A: gates of L0(I+1) -> regs; emb(I+2) -> XA[I&1].x (waves 0-3)
  auto GEMM0R = [&](const int I){
    const int Px = (I+1)&1, Pr = I&1;
    const __bf16* xbuf = &XA[Px][0][0];
    const __bf16* hbuf = &XA[Pr][0][0];
    bf16x8 ax0 = *(const bf16x8*)(xbuf + rx + gA0);
    bf16x8 ax1 = *(const bf16x8*)(xbuf + rx + gA1);
    bf16x8 ah0 = *(const bf16x8*)(hbuf + rx + 64 + gA0);
    bf16x8 ah1 = *(const bf16x8*)(hbuf + rx + 64 + gA1);
    f32x4 A0 = sp(gb[0]), A1 = sp(gb[1]);
    A0=MFMA16(ax0,wf[0],A0); A1=MFMA16(ax0,wf[4],A1);
    A0=MFMA16(ax1,wf[1],A0); A1=MFMA16(ax1,wf[5],A1);
    A0=MFMA16(ah0,wf[2],A0); A1=MFMA16(ah0,wf[6],A1);
    A0=MFMA16(ah1,wf[3],A0); A1=MFMA16(ah1,wf[7],A1);
    if (I < 510 && w < 4){
      const int s = I&1;
      f32x4 xr0 = s ? pa1 : pa0, xr1 = s ? pb1 : pb0;
      f32x4 ea = MFMA16(cvt8(xr0,xr1), wembf, sp(eb));
      int tn = I+4; if (tn > 511) tn = 511;
      f32x4 na = *(const f32x4*)(xb + (size_t)tn*32);
      f32x4 nb = *(const f32x4*)(xb + (size_t)tn*32 + 4);
      if (s){ pa1=na; pb1=nb; } else { pa0=na; pb0=nb; }
      if (quad < 2){
#pragma unroll
        for (int r=0; r<4; ++r){
          const int rr = quad*4 + r;
          XA[s][rr][((gue ^ rr) << 3) | oue] = (__bf16)ea[r];
        }
      }
    }
    A0h = A0; A1h = A1;
  };

  // grp0 phase B: EW -> h0(I+1) at parity (I+1)&1
  auto EW0S = [&](const int I){
    (&XA[(I+1)&1][0][0])[sw0] = (__bf16)EWF(cC);
  };

  // grp1 phase B: gates of L1(I) = [h0(I) | h1(I-1)] -> regs
  auto GEMM1R = [&](const int I){
    const int Pr = I&1, Ph = (I+1)&1;   // h1(I-1) parity = (I-1)&1 = (I+1)&1
    const __bf16* hbuf = &XA[Pr][0][0];
    const __bf16* gbuf = &H1s[Ph][0][0];
    bf16x8 ah0 = *(const bf16x8*)(hbuf + rx + 64 + gA0);
    bf16x8 ah1 = *(const bf16x8*)(hbuf + rx + 64 + gA1);
    bf16x8 ag0 = *(const bf16x8*)(gbuf + rh + gA0);
    bf16x8 ag1 = *(const bf16x8*)(gbuf + rh + gA1);
    f32x4 A0 = sp(gb[0]), A1 = sp(gb[1]);
    A0=MFMA16(ah0,wf[0],A0); A1=MFMA16(ah0,wf[4],A1);
    A0=MFMA16(ah1,wf[1],A0); A1=MFMA16(ah1,wf[5],A1);
    A0=MFMA16(ag0,wf[2],A0); A1=MFMA16(ag0,wf[6],A1);
    A0=MFMA16(ag1,wf[3],A0); A1=MFMA16(ag1,wf[7],A1);
    A0h = A0; A1h = A1;
  };

  // grp1 phase A (next slot): EW -> h1(I) at parity I&1
  auto EW1S = [&](const int I){
    (&H1s[I&1][0][0])[sw1] = (__bf16)EWF(cC);
  };

  __syncthreads();                 // zero-init visible

  // ---- prologue ----
  if (w < 4){
    f32x4 x0a = *(const f32x4*)xb, x0b = *(const f32x4*)(xb+4);
    f32x4 e0 = MFMA16(cvt8(x0a,x0b), wembf, sp(eb));
    if (quad < 2){
#pragma unroll
      for (int r=0; r<4; ++r){
        const int rr = quad*4 + r;
        XA[0][rr][((gue ^ rr) << 3) | oue] = (__bf16)e0[r];
      }
    }
  }
  __syncthreads();
  if (g0) GEMM0R(-1);              // gates L0(0); emb(1) -> XA[1].x
  __syncthreads();
  if (g0) EW0S(-1);                // h0(0) -> parity 0
  __syncthreads();

  // ---- steady encoder: 2 anti-phase barriers per slot ----
  if (g0) GEMM0R(0);
  __syncthreads();
  if (g0) EW0S(0); else GEMM1R(0);
  __syncthreads();
  for (int I=1; I<511; ++I){
    if (g0) GEMM0R(I); else EW1S(I-1);
    __syncthreads();
    if (g0) EW0S(I); else GEMM1R(I);
    __syncthreads();
  }

  // ---- epilogue: finish L1(510), run L1(511) ----
  if (!g0) EW1S(510);              // h1(510) par 0
  __syncthreads();
  if (!g0) GEMM1R(511);            // reads h0(511) par 1, h1(510) par 0
  __syncthreads();
  if (!g0) EW1S(511);              // h1(511) par 1
  __syncthreads();

  // ================= decoder =================
  // init: XA[1].x = h1(511). Phys-to-phys copy is valid: x-part and H1s use
  // the identical group swizzle (slot j holds logical group j^row in both).
  for (int idx = tid; idx < 8*64; idx += 1024){
    XA[1][idx>>6][idx&63] = H1s[1][idx>>6][idx&63];
  }
  // regression head (loaded late to keep encoder reg pressure low)
  bf16x8 wr0 = ld8(Wreg + (col&7)*64 +  0 + quad*8);
  bf16x8 wr1 = ld8(Wreg + (col&7)*64 + 32 + quad*8);
  const float rb = breg[col&7];
  // decoder: wave w owns 4 units (both layers), 16 gate-permuted cols:
  // col = [i(4) | f(4) | g(4) | o(4)], n = 64*(col>>2) + 4*w + (col&3)
  float gbd[2];
#pragma unroll
  for (int l=0; l<2; ++l){
    const int n = 64*(col>>2) + 4*w + (col&3);
    gbd[l] = dbih[l*256+n] + dbhh[l*256+n];
#pragma unroll
    for (int ks=0; ks<4; ++ks){
      const float* srcw = (ks < 2) ? dWih : dWhh;
      wf[l*4+ks] = ld8(srcw + ((size_t)(l*256+n))*64 + (ks&1)*32 + quad*8);
    }
  }
  // decoder fused-EW lane roles: gate = col>>2; 2x redundancy, writer = even gate
  const int  gated = col >> 2;
  const bool b0d = (gated & 1) != 0;
  const bool b1d = (gated & 2) != 0;     // sr bit0
  const int  rd  = 4*(quad & 1) + (b1d ? 1 : 0) + (qhb ? 2 : 0);
  const int  udj = 4*w + (col & 3);
  const int  gdd = udj >> 3;
  const int  swdx = rd*128 + 64 + ((gdd ^ rd) << 3) + (udj & 7);  // h0 store
  const int  swdh = rd*64       + ((gdd ^ rd) << 3) + (udj & 7);  // h1 store
  const int  swdi = rd*128      + ((gdd ^ rd) << 3) + (udj & 7);  // input store
  float cD0 = 0.f, cD1 = 0.f;
  __syncthreads();

  // 4-gate gather: xor-4 (swz) for gate^1, xor-8 (DPP) for gate^2/^3
  auto EWD = [&](f32x4 B, float& c) -> float {
    float lo  = qhb ? B[2] : B[0];
    float hi2 = qhb ? B[3] : B[1];
    float a  = b1d ? hi2 : lo;           // own gate, elem sr
    float ax = b1d ? lo  : hi2;          // own gate, elem sr^1
    float pA = swz4(a);                  // gate^1 @ sr
    float pB = swz4(ax);                 // gate^1 @ sr^1
    float qA = dppx8(ax);                // gate^2 @ sr
    float qB = dppx8(pB);                // gate^3 @ sr
    float gi = b1d ? (b0d?qB:qA) : (b0d?pA:a);
    float gf = b1d ? (b0d?qA:qB) : (b0d?a:pA);
    float gg = b1d ? (b0d?pA:a) : (b0d?qB:qA);
    float go = b1d ? (b0d?a:pA) : (b0d?qA:qB);
    float i0 = sigm(gi), f0 = sigm(gf), gt = tanhx(gg), o0 = sigm(go);
    c = f0*c + i0*gt;
    return o0*tanhx(c);
  };

  auto Ystore = [&](const int t){
    const int hp = t&1;
    const __bf16* hb_ = &H1s[hp][0][0];
    f32x4 ya = sp(rb);
    bf16x8 y0 = *(const bf16x8*)(hb_ + rh + gA0);
    bf16x8 y1 = *(const bf16x8*)(hb_ + rh + gA1);
    ya = MFMA16(y0, wr0, ya);
    ya = MFMA16(y1, wr1, ya);
    if (quad < 2 && col < 8){
#pragma unroll
      for (int r=0; r<4; ++r)
        out[((size_t)(b0 + quad*4 + r)*48 + t)*8 + col] = ya[r];
    }
  };

  // per step: 2 fused phases. h0/h1/input all parity-double-buffered.
#define DSTEP(T) {                                                         \
    const int P = (T)&1, Pm = P^1;                                         \
    {                                                                      \
      const __bf16* xb_ = &XA[Pm][0][0];                                   \
      bf16x8 ax0 = *(const bf16x8*)(xb_ + rx + gA0);                       \
      bf16x8 ax1 = *(const bf16x8*)(xb_ + rx + gA1);                       \
      bf16x8 ah0 = *(const bf16x8*)(xb_ + rx + 64 + gA0);                  \
      bf16x8 ah1 = *(const bf16x8*)(xb_ + rx + 64 + gA1);                  \
      f32x4 B0 = sp(gbd[0]);                                               \
      B0=MFMA16(ax0,wf[0],B0); B0=MFMA16(ax1,wf[1],B0);                    \
      B0=MFMA16(ah0,wf[2],B0); B0=MFMA16(ah1,wf[3],B0);                    \
      float h = EWD(B0, cD0);                                              \
      if (!b0d) (&XA[P][0][0])[swdx] = (__bf16)h;                          \
      if ((T) && w == 0) Ystore((T)-1);                                    \
    }                                                                      \
    __syncthreads();                                                       \
    {                                                                      \
      const __bf16* xb_ = &XA[P][0][0];                                    \
      const __bf16* hb_ = &H1s[Pm][0][0];                                  \
      bf16x8 ah0 = *(const bf16x8*)(xb_ + rx + 64 + gA0);                  \
      bf16x8 ah1 = *(const bf16x8*)(xb_ + rx + 64 + gA1);                  \
      bf16x8 ag0 = *(const bf16x8*)(hb_ + rh + gA0);                       \
      bf16x8 ag1 = *(const bf16x8*)(hb_ + rh + gA1);                       \
      f32x4 B1 = sp(gbd[1]);                                               \
      B1=MFMA16(ah0,wf[4],B1); B1=MFMA16(ah1,wf[5],B1);                    \
      B1=MFMA16(ag0,wf[6],B1); B1=MFMA16(ag1,wf[7],B1);                    \
      float h = EWD(B1, cD1);                                              \
      if (!b0d){ (&H1s[P][0][0])[swdh] = (__bf16)h;                        \
                 (&XA[P][0][0])[swdi]  = (__bf16)h; }                      \
    }                                                                      \
    __syncthreads();                                                       \
  }

  for (int tt=0; tt<24; ++tt){
    DSTEP(2*tt)
    DSTEP(2*tt+1)
  }
#undef DSTEP
  if (w == 0) Ystore(47);
}

extern "C" void kernel_launch(void* const* d_in, const int* in_sizes, int n_in,
                              void* d_out, int out_size, void* d_ws, size_t ws_size,
                              hipStream_t stream)
{
  (void)in_sizes; (void)n_in; (void)out_size; (void)d_ws; (void)ws_size;
  const float* X    = (const float*)d_in[0];
  const float* Wemb = (const float*)d_in[2];
  const float* bemb = (const float*)d_in[3];
  const float* eWih = (const float*)d_in[4];
  const float* eWhh = (const float*)d_in[5];
  const float* ebih = (const float*)d_in[6];
  const float* ebhh = (const float*)d_in[7];
  const float* dWih = (const float*)d_in[8];
  const float* dWhh = (const float*)d_in[9];
  const float* dbih = (const float*)d_in[10];
  const float* dbhh = (const float*)d_in[11];
  const float* Wreg = (const float*)d_in[12];
  const float* breg = (const float*)d_in[13];
  float* out = (float*)d_out;

  seq2seq_kernel<<<dim3(256), dim3(1024), 0, stream>>>(
      X, Wemb, bemb, eWih, eWhh, ebih, ebhh,
      dWih, dWhh, dbih, dbhh, Wreg, breg, out);
}

// Round 3
// 829.241 us; speedup vs baseline: 1.0932x; 1.0932x over previous
//
#include <hip/hip_runtime.h>
#include <hip/hip_bf16.h>

typedef __bf16 bf16x8 __attribute__((ext_vector_type(8)));
typedef float  f32x4  __attribute__((ext_vector_type(4)));

#define MFMA16(a,b,c) __builtin_amdgcn_mfma_f32_16x16x32_bf16((a),(b),(c),0,0,0)

#if __has_builtin(__builtin_amdgcn_exp2f)
#define EXP2(x) __builtin_amdgcn_exp2f(x)
#else
#define EXP2(x) exp2f(x)
#endif
#define RCP(x) __builtin_amdgcn_rcpf(x)

#define KL  1.44269504088896340736f   /* log2(e)   */
#define K2L 2.88539008177792681472f   /* 2*log2(e) */

__device__ __forceinline__ bf16x8 cvt8(f32x4 a, f32x4 b){
  bf16x8 r;
  r[0]=(__bf16)a[0]; r[1]=(__bf16)a[1]; r[2]=(__bf16)a[2]; r[3]=(__bf16)a[3];
  r[4]=(__bf16)b[0]; r[5]=(__bf16)b[1]; r[6]=(__bf16)b[2]; r[7]=(__bf16)b[3];
  return r;
}
__device__ __forceinline__ f32x4 sp(float v){ return (f32x4){v,v,v,v}; }
__device__ __forceinline__ bf16x8 ld8(const float* p){
  return cvt8(*(const f32x4*)p, *(const f32x4*)(p+4));
}
// scaled load: 8 f32 -> *s -> bf16x8  (weights pre-scaled by log2e factors)
__device__ __forceinline__ bf16x8 ld8s(const float* p, float s){
  f32x4 a = *(const f32x4*)p, b = *(const f32x4*)(p+4);
  return cvt8(a*sp(s), b*sp(s));
}

// LSTM elementwise with PRE-SCALED gates: gi,gf,go are log2e*(true gate),
// gg is 2*log2e*(true g). Shared-denominator form: 5 exp2 + 3 rcp (was 5+5).
// sigma(f)*c + sigma(i)*tanh(g) = c*rcp(1+Ef) + (G-1)*rcp((1+Ei)(1+G))
// sigma(o)*tanh(c')            = (C2-1)*rcp((1+Eo)(1+C2))
// Clamps: gg at +-60 (tanh(20.8) == 1.0f exactly), c' at +-30 for the tanh
// input only (tanh(30) == 1.0f exactly) -> no overflow-NaN, saturation exact.
__device__ __forceinline__ float lstm_ew(float gi, float gf, float gg,
                                         float go, float& c){
  float Ef = EXP2(-gf);
  float Ei = EXP2(-gi);
  float gc = fminf(fmaxf(gg, -60.f), 60.f);
  float G  = EXP2(gc);
  float Rf = RCP(1.f + Ef);
  float Rig= RCP((1.f + Ei) * (1.f + G));
  c = c*Rf + (G - 1.f)*Rig;
  float Eo = EXP2(-go);
  float ch = fminf(fmaxf(c, -30.f), 30.f);
  float C2 = EXP2(ch * K2L);
  return (C2 - 1.f) * RCP((1.f + Eo) * (1.f + C2));
}

// lane^8 exchange within each 16-lane row: DPP row_ror:8 (VALU pipe, no LDS)
__device__ __forceinline__ float dppx8(float v){
  return __int_as_float(__builtin_amdgcn_update_dpp(
      0, __float_as_int(v), 0x128, 0xF, 0xF, true));
}
// lane^4 exchange: ds_swizzle xor-4 (decoder only)
__device__ __forceinline__ float swz4(float v){
  return __int_as_float(__builtin_amdgcn_ds_swizzle(__float_as_int(v), 0x101F));
}

// R3 = R1's proven single-barrier fused schedule, minus work:
//  - Wemb folded into L0 input weights: W' = eWih0 @ Wemb (256x32, K=32),
//    bias' = eWih0@bemb + bih + bhh. x-fragment comes straight from global
//    (L1-cached, prefetched 2 slots ahead). Emb pass + 2 LDS reads/wave gone.
//  - EW: shared-denominator form, 8 transcendentals/cell (was 10).
//  - all gate weights/biases pre-scaled by log2e (2*log2e for g) so exp is a
//    bare v_exp_f32.
// Schedule/LDS layout identical to the measured-459us R1 kernel.
extern "C" __global__ void __launch_bounds__(1024, 4)
seq2seq_kernel(const float* __restrict__ X,
               const float* __restrict__ Wemb, const float* __restrict__ bemb,
               const float* __restrict__ eWih, const float* __restrict__ eWhh,
               const float* __restrict__ ebih, const float* __restrict__ ebhh,
               const float* __restrict__ dWih, const float* __restrict__ dWhh,
               const float* __restrict__ dbih, const float* __restrict__ dbhh,
               const float* __restrict__ Wreg, const float* __restrict__ breg,
               float* __restrict__ out)
{
  // XA[parity][row][136]: cols 0-63 = decoder input, 64-127 = h0.
  __shared__ __align__(16) __bf16 XA[2][8][136];
  __shared__ __align__(16) __bf16 H1s[2][8][72];

  const int tid  = (int)threadIdx.x;
  const int w    = tid >> 6;         // 0..15
  const int grp  = w >> 3;           // 0: layer0 group, 1: layer1 group
  const bool g0  = (grp == 0);
  const int wt   = w & 7;            // wave-in-group; units u0 = 8*wt
  const int lane = tid & 63;
  const int col  = lane & 15;
  const int quad = lane >> 4;
  const int row8 = col & 7;          // A real row (M=16 mirrors 8 rows)
  const int b0   = (int)blockIdx.x * 8;
  const int brow = b0 + row8;

  // fused-EW lane roles (encoder): cell = (row ewr, unit ewu)
  const bool hib = (col & 8) != 0;       // sr bit0
  const bool qhb = (quad & 2) != 0;      // sr bit1
  const int  ewr = 4*(quad & 1) + (hib ? 1 : 0) + (qhb ? 2 : 0);
  const int  ewu = 8*wt + (col & 7);

  for (int i = tid; i < 2*8*136; i += 1024) (&XA[0][0][0])[i]  = (__bf16)0.f;
  for (int i = tid; i < 2*8*72;  i += 1024) (&H1s[0][0][0])[i] = (__bf16)0.f;

  // ---- persistent weight fragments ----
  // gate-permuted col: n = 64*gate + unit, gate = 2*ti + (col>>3)
  // grp0: wf[ti*4+0] = W' x-frag (K=32); wf[ti*4+2/3] = Whh frags.
  // grp1: wf[ti*4+0..3] = [Wih | Whh] K=128 as in R1.
  bf16x8 wf[8];
  float  gb[2];
#pragma unroll
  for (int ti=0; ti<2; ++ti){
    const int gate = 2*ti + (col>>3);
    const int n = 64*gate + 8*wt + (col&7);
    const float sc = (gate == 2) ? K2L : KL;
    if (g0){
      // fold: W'[n][f] = sum_k eWih0[n][k] * Wemb[k][f], f = quad*8..+7
      //       bx      = sum_k eWih0[n][k] * bemb[k]
      f32x4 acL = sp(0.f), acH = sp(0.f);
      float bx = 0.f;
      const float* wr_ = eWih + (size_t)n*64;
      for (int k=0; k<64; ++k){
        float a = wr_[k];
        bx += a * bemb[k];
        f32x4 m0 = *(const f32x4*)(Wemb + k*32 + quad*8);
        f32x4 m1 = *(const f32x4*)(Wemb + k*32 + quad*8 + 4);
        acL += sp(a)*m0; acH += sp(a)*m1;
      }
      wf[ti*4+0] = cvt8(acL*sp(sc), acH*sp(sc));
      wf[ti*4+2] = ld8s(eWhh + (size_t)n*64 +      quad*8, sc);
      wf[ti*4+3] = ld8s(eWhh + (size_t)n*64 + 32 + quad*8, sc);
      gb[ti] = (ebih[n] + ebhh[n] + bx) * sc;
    } else {
      const int m = 256 + n;
      wf[ti*4+0] = ld8s(eWih + (size_t)m*64 +      quad*8, sc);
      wf[ti*4+1] = ld8s(eWih + (size_t)m*64 + 32 + quad*8, sc);
      wf[ti*4+2] = ld8s(eWhh + (size_t)m*64 +      quad*8, sc);
      wf[ti*4+3] = ld8s(eWhh + (size_t)m*64 + 32 + quad*8, sc);
      gb[ti] = (ebih[m] + ebhh[m]) * sc;
    }
  }

  // raw-x prefetch (grp0 waves): pair parity p holds x(t) with t&1 == p
  const float* xb = X + (size_t)brow*512*32 + quad*8;
  f32x4 pa0, pb0, pa1, pb1;
  if (g0){
    pa0 = *(const f32x4*)(xb);     pb0 = *(const f32x4*)(xb+4);    // x(0)
    pa1 = *(const f32x4*)(xb+32);  pb1 = *(const f32x4*)(xb+36);   // x(1)
  }

  float cC = 0.f;   // grp0: c0 of cell (ewr,ewu); grp1: c1

  // in-register EW: gather (i,f,g,o) for this lane's cell via DPP xor-8.
  auto EWF = [&](f32x4 A0, f32x4 A1, float& c) -> float {
    float lo0 = qhb ? A0[2] : A0[0];
    float hi0 = qhb ? A0[3] : A0[1];
    float lo1 = qhb ? A1[2] : A1[0];
    float hi1 = qhb ? A1[3] : A1[1];
    float a0s = hib ? hi0 : lo0, a0x = hib ? lo0 : hi0;
    float a1s = hib ? hi1 : lo1, a1x = hib ? lo1 : hi1;
    float r0 = dppx8(a0x), r1 = dppx8(a1x);
    float gi = hib ? r0  : a0s;
    float gf = hib ? a0s : r0;
    float gg = hib ? r1  : a1s;
    float go = hib ? a1s : r1;
    return lstm_ew(gi, gf, gg, go, c);
  };

  // grp0 slot I: L0(I+1) from x(I+1)[regs] & h0(I)[LDS] -> h0(I+1)
  auto FUSED0 = [&](const int I){
    const int Px = (I+1)&1, Pr = I&1;
    f32x4 xr0 = Px ? pa1 : pa0, xr1 = Px ? pb1 : pb0;
    bf16x8 axf = cvt8(xr0, xr1);
    { // prefetch x(I+3) into the pair just consumed
      int tn = I+3; if (tn > 511) tn = 511;
      f32x4 na = *(const f32x4*)(xb + (size_t)tn*32);
      f32x4 nb = *(const f32x4*)(xb + (size_t)tn*32 + 4);
      if (Px){ pa1=na; pb1=nb; } else { pa0=na; pb0=nb; }
    }
    bf16x8 ah0 = *(const bf16x8*)&XA[Pr][row8][64 + quad*8];
    bf16x8 ah1 = *(const bf16x8*)&XA[Pr][row8][96 + quad*8];
    f32x4 A0 = sp(gb[0]), A1 = sp(gb[1]);
    A0=MFMA16(axf,wf[0],A0); A1=MFMA16(axf,wf[4],A1);
    A0=MFMA16(ah0,wf[2],A0); A1=MFMA16(ah0,wf[6],A1);
    A0=MFMA16(ah1,wf[3],A0); A1=MFMA16(ah1,wf[7],A1);
    XA[Px][ewr][64+ewu] = (__bf16)EWF(A0, A1, cC);
  };

  // grp1 slot I: L1(I) = [h0(I) | h1(I-1)] -> h1(I) at parity I&1
  auto FUSED1 = [&](const int I){
    const int Px = (I+1)&1, Pr = I&1;
    bf16x8 ah0 = *(const bf16x8*)&XA[Pr][row8][64 + quad*8];
    bf16x8 ah1 = *(const bf16x8*)&XA[Pr][row8][96 + quad*8];
    bf16x8 ag0 = *(const bf16x8*)&H1s[Px][row8][quad*8];
    bf16x8 ag1 = *(const bf16x8*)&H1s[Px][row8][32 + quad*8];
    f32x4 A0 = sp(gb[0]), A1 = sp(gb[1]);
    A0=MFMA16(ah0,wf[0],A0); A1=MFMA16(ah0,wf[4],A1);
    A0=MFMA16(ah1,wf[1],A0); A1=MFMA16(ah1,wf[5],A1);
    A0=MFMA16(ag0,wf[2],A0); A1=MFMA16(ag0,wf[6],A1);
    A0=MFMA16(ag1,wf[3],A0); A1=MFMA16(ag1,wf[7],A1);
    H1s[Pr][ewr][ewu] = (__bf16)EWF(A0, A1, cC);
  };

  __syncthreads();                 // zero-init visible

  // ---- prologue: L0(0) from x(0), h0(-1)=0 ----
  if (g0) FUSED0(-1);              // h0(0) -> parity 0
  __syncthreads();

  // ---- steady encoder: slot I -> h0(I+1) & h1(I); ONE barrier/slot ----
#define SLOT(I) { if (g0) FUSED0(I); else FUSED1(I); __syncthreads(); }
  for (int ii=0; ii<255; ++ii){
    SLOT(2*ii)
    SLOT(2*ii+1)
  }
  SLOT(510)
#undef SLOT

  // ---- epilogue: h1(511) ----
  if (!g0) FUSED1(511);            // reads h0(511) (par 1), h1(510) (par 0)
  __syncthreads();

  // ================= decoder =================
  // init: XA[1] = [input=h1(511) | h0(511)] (h0(511) already at XA[1][64..])
  for (int idx = tid; idx < 8*64; idx += 1024){
    XA[1][idx>>6][idx&63] = H1s[1][idx>>6][idx&63];
  }
  // regression head (unscaled)
  bf16x8 wr0 = ld8(Wreg + (col&7)*64 +  0 + quad*8);
  bf16x8 wr1 = ld8(Wreg + (col&7)*64 + 32 + quad*8);
  const float rb = breg[col&7];
  // decoder: wave w owns 4 units (both layers), 16 gate-permuted cols:
  // col = [i(4) | f(4) | g(4) | o(4)], n = 64*(col>>2) + 4*w + (col&3)
  const int  gated = col >> 2;
  const float scd = (gated == 2) ? K2L : KL;
  float gbd[2];
#pragma unroll
  for (int l=0; l<2; ++l){
    const int n = 64*gated + 4*w + (col&3);
    gbd[l] = (dbih[l*256+n] + dbhh[l*256+n]) * scd;
#pragma unroll
    for (int ks=0; ks<4; ++ks){
      const float* srcw = (ks < 2) ? dWih : dWhh;
      wf[l*4+ks] = ld8s(srcw + ((size_t)(l*256+n))*64 + (ks&1)*32 + quad*8, scd);
    }
  }
  // decoder fused-EW lane roles: 2x redundancy, writer = even gate
  const bool b0d = (gated & 1) != 0;
  const bool b1d = (gated & 2) != 0;     // sr bit0
  const int  rd  = 4*(quad & 1) + (b1d ? 1 : 0) + (qhb ? 2 : 0);
  const int  udj = 4*w + (col & 3);
  float cD0 = 0.f, cD1 = 0.f;
  __syncthreads();

  // 4-gate gather: xor-4 (swz) for gate^1, xor-8 (DPP) for gate^2/^3
  auto EWD = [&](f32x4 B, float& c) -> float {
    float lo  = qhb ? B[2] : B[0];
    float hi2 = qhb ? B[3] : B[1];
    float a  = b1d ? hi2 : lo;           // own gate, elem sr
    float ax = b1d ? lo  : hi2;          // own gate, elem sr^1
    float pA = swz4(a);                  // gate^1 @ sr
    float pB = swz4(ax);                 // gate^1 @ sr^1
    float qA = dppx8(ax);                // gate^2 @ sr
    float qB = dppx8(pB);                // gate^3 @ sr
    float gi = b1d ? (b0d?qB:qA) : (b0d?pA:a);
    float gf = b1d ? (b0d?qA:qB) : (b0d?a:pA);
    float gg = b1d ? (b0d?pA:a) : (b0d?qB:qA);
    float go = b1d ? (b0d?a:pA) : (b0d?qA:qB);
    return lstm_ew(gi, gf, gg, go, c);
  };

  auto Ystore = [&](const int t){
    const int hp = t&1;
    f32x4 ya = sp(rb);
    bf16x8 y0 = *(const bf16x8*)&H1s[hp][row8][quad*8];
    bf16x8 y1 = *(const bf16x8*)&H1s[hp][row8][32 + quad*8];
    ya = MFMA16(y0, wr0, ya);
    ya = MFMA16(y1, wr1, ya);
    if (quad < 2 && col < 8){
#pragma unroll
      for (int r=0; r<4; ++r)
        out[((size_t)(b0 + quad*4 + r)*48 + t)*8 + col] = ya[r];
    }
  };

  // per step: 2 fused phases. h0/h1/input all parity-double-buffered.
#define DSTEP(T) {                                                         \
    const int P = (T)&1, Pm = P^1;                                         \
    {                                                                      \
      bf16x8 ax0 = *(const bf16x8*)&XA[Pm][row8][ 0 + quad*8];             \
      bf16x8 ax1 = *(const bf16x8*)&XA[Pm][row8][32 + quad*8];             \
      bf16x8 ah0 = *(const bf16x8*)&XA[Pm][row8][64 + quad*8];             \
      bf16x8 ah1 = *(const bf16x8*)&XA[Pm][row8][96 + quad*8];             \
      f32x4 B0 = sp(gbd[0]);                                               \
      B0=MFMA16(ax0,wf[0],B0); B0=MFMA16(ax1,wf[1],B0);                    \
      B0=MFMA16(ah0,wf[2],B0); B0=MFMA16(ah1,wf[3],B0);                    \
      float h = EWD(B0, cD0);                                              \
      if (!b0d) XA[P][rd][64+udj] = (__bf16)h;                             \
      if ((T) && w == 0) Ystore((T)-1);                                    \
    }                                                                      \
    __syncthreads();                                                       \
    {                                                                      \
      bf16x8 ah0 = *(const bf16x8*)&XA[P][row8][64 + quad*8];              \
      bf16x8 ah1 = *(const bf16x8*)&XA[P][row8][96 + quad*8];              \
      bf16x8 ag0 = *(const bf16x8*)&H1s[Pm][row8][ 0 + quad*8];            \
      bf16x8 ag1 = *(const bf16x8*)&H1s[Pm][row8][32 + quad*8];            \
      f32x4 B1 = sp(gbd[1]);                                               \
      B1=MFMA16(ah0,wf[4],B1); B1=MFMA16(ah1,wf[5],B1);                    \
      B1=MFMA16(ag0,wf[6],B1); B1=MFMA16(ag1,wf[7],B1);                    \
      float h = EWD(B1, cD1);                                              \
      if (!b0d){ H1s[P][rd][udj] = (__bf16)h; XA[P][rd][udj] = (__bf16)h; }\
    }                                                                      \
    __syncthreads();                                                       \
  }

  for (int tt=0; tt<24; ++tt){
    DSTEP(2*tt)
    DSTEP(2*tt+1)
  }
#undef DSTEP
  if (w == 0) Ystore(47);
}

extern "C" void kernel_launch(void* const* d_in, const int* in_sizes, int n_in,
                              void* d_out, int out_size, void* d_ws, size_t ws_size,
                              hipStream_t stream)
{
  (void)in_sizes; (void)n_in; (void)out_size; (void)d_ws; (void)ws_size;
  const float* X    = (const float*)d_in[0];
  const float* Wemb = (const float*)d_in[2];
  const float* bemb = (const float*)d_in[3];
  const float* eWih = (const float*)d_in[4];
  const float* eWhh = (const float*)d_in[5];
  const float* ebih = (const float*)d_in[6];
  const float* ebhh = (const float*)d_in[7];
  const float* dWih = (const float*)d_in[8];
  const float* dWhh = (const float*)d_in[9];
  const float* dbih = (const float*)d_in[10];
  const float* dbhh = (const float*)d_in[11];
  const float* Wreg = (const float*)d_in[12];
  const float* breg = (const float*)d_in[13];
  float* out = (float*)d_out;

  seq2seq_kernel<<<dim3(256), dim3(1024), 0, stream>>>(
      X, Wemb, bemb, eWih, eWhh, ebih, ebhh,
      dWih, dWhh, dbih, dbhh, Wreg, breg, out);
}

// Round 4
// 602.937 us; speedup vs baseline: 1.5035x; 1.3753x over previous
//
#include <hip/hip_runtime.h>
#include <hip/hip_bf16.h>

typedef __bf16 bf16x8 __attribute__((ext_vector_type(8)));
typedef float  f32x4  __attribute__((ext_vector_type(4)));

#define MFMA16(a,b,c) __builtin_amdgcn_mfma_f32_16x16x32_bf16((a),(b),(c),0,0,0)

#if __has_builtin(__builtin_amdgcn_exp2f)
#define EXP2(x) __builtin_amdgcn_exp2f(x)
#else
#define EXP2(x) exp2f(x)
#endif
#define RCP(x) __builtin_amdgcn_rcpf(x)

#define KL  1.44269504088896340736f   /* log2(e)   */
#define K2L 2.88539008177792681472f   /* 2*log2(e) */

__device__ __forceinline__ bf16x8 cvt8(f32x4 a, f32x4 b){
  bf16x8 r;
  r[0]=(__bf16)a[0]; r[1]=(__bf16)a[1]; r[2]=(__bf16)a[2]; r[3]=(__bf16)a[3];
  r[4]=(__bf16)b[0]; r[5]=(__bf16)b[1]; r[6]=(__bf16)b[2]; r[7]=(__bf16)b[3];
  return r;
}
__device__ __forceinline__ f32x4 sp(float v){ return (f32x4){v,v,v,v}; }
__device__ __forceinline__ bf16x8 ld8(const float* p){
  return cvt8(*(const f32x4*)p, *(const f32x4*)(p+4));
}
// scaled load: 8 f32 -> *s -> bf16x8  (gate weights pre-scaled by log2e)
__device__ __forceinline__ bf16x8 ld8s(const float* p, float s){
  f32x4 a = *(const f32x4*)p, b = *(const f32x4*)(p+4);
  return cvt8(a*sp(s), b*sp(s));
}

// LSTM elementwise with PRE-SCALED gates: gi,gf,go are log2e*(true gate),
// gg is 2*log2e*(true g). Shared-denominator form: 5 exp2 + 3 rcp (was 5+5).
// sigma(f)*c + sigma(i)*tanh(g) = c*rcp(1+Ef) + (G-1)*rcp((1+Ei)(1+G))
// sigma(o)*tanh(c')            = (C2-1)*rcp((1+Eo)(1+C2))
// Clamps: gg at +-60 and tanh-input c at +-30 -> no overflow, saturation
// exact in fp32 (tanh(20.8)==tanh(30)==1.0f). Validated in R3 (same absmax).
__device__ __forceinline__ float lstm_ew(float gi, float gf, float gg,
                                         float go, float& c){
  float Ef = EXP2(-gf);
  float Ei = EXP2(-gi);
  float gc = fminf(fmaxf(gg, -60.f), 60.f);
  float G  = EXP2(gc);
  float Rf = RCP(1.f + Ef);
  float Rig= RCP((1.f + Ei) * (1.f + G));
  c = c*Rf + (G - 1.f)*Rig;
  float Eo = EXP2(-go);
  float ch = fminf(fmaxf(c, -30.f), 30.f);
  float C2 = EXP2(ch * K2L);
  return (C2 - 1.f) * RCP((1.f + Eo) * (1.f + C2));
}

// lane^8 exchange within each 16-lane row: DPP row_ror:8 (VALU pipe, no LDS)
__device__ __forceinline__ float dppx8(float v){
  return __int_as_float(__builtin_amdgcn_update_dpp(
      0, __float_as_int(v), 0x128, 0xF, 0xF, true));
}
// lane^4 exchange: ds_swizzle xor-4 (decoder only)
__device__ __forceinline__ float swz4(float v){
  return __int_as_float(__builtin_amdgcn_ds_swizzle(__float_as_int(v), 0x101F));
}

// R4 = the measured-459us R1 kernel with EXACTLY ONE change: the EW math
// (pre-scaled gates + shared-denominator form, 8 transcendentals/cell vs 10).
// Schedule, LDS layout, emb path, prefetching, barriers: identical to R1.
extern "C" __global__ void __launch_bounds__(1024, 4)
seq2seq_kernel(const float* __restrict__ X,
               const float* __restrict__ Wemb, const float* __restrict__ bemb,
               const float* __restrict__ eWih, const float* __restrict__ eWhh,
               const float* __restrict__ ebih, const float* __restrict__ ebhh,
               const float* __restrict__ dWih, const float* __restrict__ dWhh,
               const float* __restrict__ dbih, const float* __restrict__ dbhh,
               const float* __restrict__ Wreg, const float* __restrict__ breg,
               float* __restrict__ out)
{
  // XA[parity][row][136]: cols 0-63 = x/input, 64-127 = h0. h1 double-buffered.
  __shared__ __align__(16) __bf16 XA[2][8][136];
  __shared__ __align__(16) __bf16 H1s[2][8][72];

  const int tid  = (int)threadIdx.x;
  const int w    = tid >> 6;         // 0..15
  const int grp  = w >> 3;           // 0: layer0 group, 1: layer1 group
  const bool g0  = (grp == 0);
  const int wt   = w & 7;            // wave-in-group; units u0 = 8*wt
  const int lane = tid & 63;
  const int col  = lane & 15;
  const int quad = lane >> 4;
  const int row8 = col & 7;          // A real row (M=16 mirrors 8 rows)
  const int b0   = (int)blockIdx.x * 8;
  const int brow = b0 + row8;

  // fused-EW lane roles (encoder): cell = (row ewr, unit ewu), elem index sr
  const bool hib = (col & 8) != 0;       // sr bit0
  const bool qhb = (quad & 2) != 0;      // sr bit1
  const int  ewr = 4*(quad & 1) + (hib ? 1 : 0) + (qhb ? 2 : 0);
  const int  ewu = 8*wt + (col & 7);

  for (int i = tid; i < 2*8*136; i += 1024) (&XA[0][0][0])[i]  = (__bf16)0.f;
  for (int i = tid; i < 2*8*72;  i += 1024) (&H1s[0][0][0])[i] = (__bf16)0.f;

  // ---- persistent fragments: 2 tiles x 4 ksteps = 32 regs ----
  // gate-permuted col: n = 64*gate + unit, gate = 2*ti + (col>>3)
  bf16x8 wf[8];
  float  gb[2];
#pragma unroll
  for (int ti=0; ti<2; ++ti){
    const int gate = 2*ti + (col>>3);
    const int n = 64*gate + 8*wt + (col&7);
    const float sc = (gate == 2) ? K2L : KL;
    gb[ti] = (ebih[grp*256+n] + ebhh[grp*256+n]) * sc;
#pragma unroll
    for (int ks=0; ks<4; ++ks){
      const float* srcw = (ks < 2) ? eWih : eWhh;
      wf[ti*4+ks] = ld8s(srcw + ((size_t)(grp*256+n))*64 + (ks&1)*32 + quad*8, sc);
    }
  }

  // emb fragments: only waves 0-3 use them (emb itself stays UNSCALED;
  // the log2e scaling lives in the eWih fragments that consume it)
  const int ue = (w&3)*16 + col;
  bf16x8 wembf;
  float eb = 0.f;
  const float* xb = X + (size_t)brow*512*32 + quad*8;
  f32x4 pa0, pb0, pa1, pb1;
  if (w < 4){
    wembf = ld8(Wemb + ue*32 + quad*8);
    eb = bemb[ue];
    pa1 = *(const f32x4*)(xb+32); pb1 = *(const f32x4*)(xb+36);   // x(1)
    pa0 = *(const f32x4*)(xb+64); pb0 = *(const f32x4*)(xb+68);   // x(2)
  }

  float cC = 0.f;   // grp0: c0 of cell (ewr,ewu); grp1: c1

  // in-register EW: gather (i,f,g,o) for this lane's cell via DPP xor-8.
  // lane c<8 locally holds (i,g) at elem sr; c>=8 holds (f,o); partner c^8
  // sends its elem sr^1 (== my sr, same real row).
  auto EWF = [&](f32x4 A0, f32x4 A1, float& c) -> float {
    float lo0 = qhb ? A0[2] : A0[0];
    float hi0 = qhb ? A0[3] : A0[1];
    float lo1 = qhb ? A1[2] : A1[0];
    float hi1 = qhb ? A1[3] : A1[1];
    float a0s = hib ? hi0 : lo0, a0x = hib ? lo0 : hi0;
    float a1s = hib ? hi1 : lo1, a1x = hib ? lo1 : hi1;
    float r0 = dppx8(a0x), r1 = dppx8(a1x);
    float gi = hib ? r0  : a0s;
    float gf = hib ? a0s : r0;
    float gg = hib ? r1  : a1s;
    float go = hib ? a1s : r1;
    return lstm_ew(gi, gf, gg, go, c);
  };

  // grp0 slot I: gates+cells of L0(I+1) -> h0(I+1) at parity (I+1)&1;
  //             emb(I+2) -> XA[I&1].x (waves 0-3)
  auto FUSED0 = [&](const int I){
    const int Px = (I+1)&1, Pr = I&1;
    bf16x8 ax0 = *(const bf16x8*)&XA[Px][row8][ 0 + quad*8];
    bf16x8 ax1 = *(const bf16x8*)&XA[Px][row8][32 + quad*8];
    bf16x8 ah0 = *(const bf16x8*)&XA[Pr][row8][64 + quad*8];
    bf16x8 ah1 = *(const bf16x8*)&XA[Pr][row8][96 + quad*8];
    f32x4 A0 = sp(gb[0]), A1 = sp(gb[1]);
    A0=MFMA16(ax0,wf[0],A0); A1=MFMA16(ax0,wf[4],A1);
    A0=MFMA16(ax1,wf[1],A0); A1=MFMA16(ax1,wf[5],A1);
    A0=MFMA16(ah0,wf[2],A0); A1=MFMA16(ah0,wf[6],A1);
    A0=MFMA16(ah1,wf[3],A0); A1=MFMA16(ah1,wf[7],A1);
    if (I < 510 && w < 4){
      const int s = I&1;
      f32x4 xr0 = s ? pa1 : pa0, xr1 = s ? pb1 : pb0;
      f32x4 ea = MFMA16(cvt8(xr0,xr1), wembf, sp(eb));
      int tn = I+4; if (tn > 511) tn = 511;
      f32x4 na = *(const f32x4*)(xb + (size_t)tn*32);
      f32x4 nb = *(const f32x4*)(xb + (size_t)tn*32 + 4);
      if (s){ pa1=na; pb1=nb; } else { pa0=na; pb0=nb; }
      if (quad < 2){
#pragma unroll
        for (int r=0; r<4; ++r) XA[s][quad*4+r][ue] = (__bf16)ea[r];
      }
    }
    XA[Px][ewr][64+ewu] = (__bf16)EWF(A0, A1, cC);
  };

  // grp1 slot I: L1(I) = [h0(I) | h1(I-1)] -> h1(I) at parity I&1
  auto FUSED1 = [&](const int I){
    const int Px = (I+1)&1, Pr = I&1;
    bf16x8 ah0 = *(const bf16x8*)&XA[Pr][row8][64 + quad*8];
    bf16x8 ah1 = *(const bf16x8*)&XA[Pr][row8][96 + quad*8];
    bf16x8 ag0 = *(const bf16x8*)&H1s[Px][row8][quad*8];
    bf16x8 ag1 = *(const bf16x8*)&H1s[Px][row8][32 + quad*8];
    f32x4 A0 = sp(gb[0]), A1 = sp(gb[1]);
    A0=MFMA16(ah0,wf[0],A0); A1=MFMA16(ah0,wf[4],A1);
    A0=MFMA16(ah1,wf[1],A0); A1=MFMA16(ah1,wf[5],A1);
    A0=MFMA16(ag0,wf[2],A0); A1=MFMA16(ag0,wf[6],A1);
    A0=MFMA16(ag1,wf[3],A0); A1=MFMA16(ag1,wf[7],A1);
    H1s[Pr][ewr][ewu] = (__bf16)EWF(A0, A1, cC);
  };

  __syncthreads();                 // zero-init visible

  // ---- prologue: emb(0), then h0(0) ----
  if (w < 4){
    f32x4 x0a = *(const f32x4*)xb, x0b = *(const f32x4*)(xb+4);
    f32x4 e0 = MFMA16(cvt8(x0a,x0b), wembf, sp(eb));
    if (quad < 2){
#pragma unroll
      for (int r=0; r<4; ++r) XA[0][quad*4+r][ue] = (__bf16)e0[r];
    }
  }
  __syncthreads();
  if (g0) FUSED0(-1);              // h0(0) -> parity 0; emb(1) -> XA[1].x
  __syncthreads();

  // ---- steady encoder: slot I -> h0(I+1) & h1(I); ONE barrier/slot ----
#define SLOT(I) { if (g0) FUSED0(I); else FUSED1(I); __syncthreads(); }
  for (int ii=0; ii<255; ++ii){
    SLOT(2*ii)
    SLOT(2*ii+1)
  }
  SLOT(510)
#undef SLOT

  // ---- epilogue: h1(511) ----
  if (!g0) FUSED1(511);            // reads h0(511) (par 1), h1(510) (par 0)
  __syncthreads();

  // ================= decoder =================
  // init: XA[1] = [input=h1(511) | h0(511)] (h0(511) already at XA[1][64..])
  for (int idx = tid; idx < 8*64; idx += 1024){
    XA[1][idx>>6][idx&63] = H1s[1][idx>>6][idx&63];
  }
  // regression head (unscaled)
  bf16x8 wr0 = ld8(Wreg + (col&7)*64 +  0 + quad*8);
  bf16x8 wr1 = ld8(Wreg + (col&7)*64 + 32 + quad*8);
  const float rb = breg[col&7];
  // decoder: wave w owns 4 units (both layers), 16 gate-permuted cols:
  // col = [i(4) | f(4) | g(4) | o(4)], n = 64*(col>>2) + 4*w + (col&3)
  const int  gated = col >> 2;
  const float scd = (gated == 2) ? K2L : KL;
  float gbd[2];
#pragma unroll
  for (int l=0; l<2; ++l){
    const int n = 64*gated + 4*w + (col&3);
    gbd[l] = (dbih[l*256+n] + dbhh[l*256+n]) * scd;
#pragma unroll
    for (int ks=0; ks<4; ++ks){
      const float* srcw = (ks < 2) ? dWih : dWhh;
      wf[l*4+ks] = ld8s(srcw + ((size_t)(l*256+n))*64 + (ks&1)*32 + quad*8, scd);
    }
  }
  // decoder fused-EW lane roles: gate = col>>2; 2x redundancy, writer = even gate
  const bool b0d = (gated & 1) != 0;
  const bool b1d = (gated & 2) != 0;     // sr bit0
  const int  rd  = 4*(quad & 1) + (b1d ? 1 : 0) + (qhb ? 2 : 0);
  const int  udj = 4*w + (col & 3);
  float cD0 = 0.f, cD1 = 0.f;
  __syncthreads();

  // 4-gate gather: xor-4 (swz) for gate^1, xor-8 (DPP) for gate^2/^3
  auto EWD = [&](f32x4 B, float& c) -> float {
    float lo  = qhb ? B[2] : B[0];
    float hi2 = qhb ? B[3] : B[1];
    float a  = b1d ? hi2 : lo;           // own gate, elem sr
    float ax = b1d ? lo  : hi2;          // own gate, elem sr^1
    float pA = swz4(a);                  // gate^1 @ sr
    float pB = swz4(ax);                 // gate^1 @ sr^1
    float qA = dppx8(ax);                // gate^2 @ sr
    float qB = dppx8(pB);                // gate^3 @ sr
    float gi = b1d ? (b0d?qB:qA) : (b0d?pA:a);
    float gf = b1d ? (b0d?qA:qB) : (b0d?a:pA);
    float gg = b1d ? (b0d?pA:a) : (b0d?qB:qA);
    float go = b1d ? (b0d?a:pA) : (b0d?qA:qB);
    return lstm_ew(gi, gf, gg, go, c);
  };

  auto Ystore = [&](const int t){
    const int hp = t&1;
    f32x4 ya = sp(rb);
    bf16x8 y0 = *(const bf16x8*)&H1s[hp][row8][quad*8];
    bf16x8 y1 = *(const bf16x8*)&H1s[hp][row8][32 + quad*8];
    ya = MFMA16(y0, wr0, ya);
    ya = MFMA16(y1, wr1, ya);
    if (quad < 2 && col < 8){
#pragma unroll
      for (int r=0; r<4; ++r)
        out[((size_t)(b0 + quad*4 + r)*48 + t)*8 + col] = ya[r];
    }
  };

  // per step: 2 fused phases. h0/h1/input all parity-double-buffered.
#define DSTEP(T) {                                                         \
    const int P = (T)&1, Pm = P^1;                                         \
    {                                                                      \
      bf16x8 ax0 = *(const bf16x8*)&XA[Pm][row8][ 0 + quad*8];             \
      bf16x8 ax1 = *(const bf16x8*)&XA[Pm][row8][32 + quad*8];             \
      bf16x8 ah0 = *(const bf16x8*)&XA[Pm][row8][64 + quad*8];             \
      bf16x8 ah1 = *(const bf16x8*)&XA[Pm][row8][96 + quad*8];             \
      f32x4 B0 = sp(gbd[0]);                                               \
      B0=MFMA16(ax0,wf[0],B0); B0=MFMA16(ax1,wf[1],B0);                    \
      B0=MFMA16(ah0,wf[2],B0); B0=MFMA16(ah1,wf[3],B0);                    \
      float h = EWD(B0, cD0);                                              \
      if (!b0d) XA[P][rd][64+udj] = (__bf16)h;                             \
      if ((T) && w == 0) Ystore((T)-1);                                    \
    }                                                                      \
    __syncthreads();                                                       \
    {                                                                      \
      bf16x8 ah0 = *(const bf16x8*)&XA[P][row8][64 + quad*8];              \
      bf16x8 ah1 = *(const bf16x8*)&XA[P][row8][96 + quad*8];              \
      bf16x8 ag0 = *(const bf16x8*)&H1s[Pm][row8][ 0 + quad*8];            \
      bf16x8 ag1 = *(const bf16x8*)&H1s[Pm][row8][32 + quad*8];            \
      f32x4 B1 = sp(gbd[1]);                                               \
      B1=MFMA16(ah0,wf[4],B1); B1=MFMA16(ah1,wf[5],B1);                    \
      B1=MFMA16(ag0,wf[6],B1); B1=MFMA16(ag1,wf[7],B1);                    \
      float h = EWD(B1, cD1);                                              \
      if (!b0d){ H1s[P][rd][udj] = (__bf16)h; XA[P][rd][udj] = (__bf16)h; }\
    }                                                                      \
    __syncthreads();                                                       \
  }

  for (int tt=0; tt<24; ++tt){
    DSTEP(2*tt)
    DSTEP(2*tt+1)
  }
#undef DSTEP
  if (w == 0) Ystore(47);
}

extern "C" void kernel_launch(void* const* d_in, const int* in_sizes, int n_in,
                              void* d_out, int out_size, void* d_ws, size_t ws_size,
                              hipStream_t stream)
{
  (void)in_sizes; (void)n_in; (void)out_size; (void)d_ws; (void)ws_size;
  const float* X    = (const float*)d_in[0];
  const float* Wemb = (const float*)d_in[2];
  const float* bemb = (const float*)d_in[3];
  const float* eWih = (const float*)d_in[4];
  const float* eWhh = (const float*)d_in[5];
  const float* ebih = (const float*)d_in[6];
  const float* ebhh = (const float*)d_in[7];
  const float* dWih = (const float*)d_in[8];
  const float* dWhh = (const float*)d_in[9];
  const float* dbih = (const float*)d_in[10];
  const float* dbhh = (const float*)d_in[11];
  const float* Wreg = (const float*)d_in[12];
  const float* breg = (const float*)d_in[13];
  float* out = (float*)d_out;

  seq2seq_kernel<<<dim3(256), dim3(1024), 0, stream>>>(
      X, Wemb, bemb, eWih, eWhh, ebih, ebhh,
      dWih, dWhh, dbih, dbhh, Wreg, breg, out);
}